// Round 15
// baseline (647.945 us; speedup 1.0000x reference)
//
#include <hip/hip_runtime.h>
#include <hip/hip_bf16.h>

typedef __attribute__((ext_vector_type(8))) short bh8;   // 8 x bf16 (4 VGPRs)
typedef __attribute__((ext_vector_type(4))) short sh4;   // 4 x bf16
typedef __attribute__((ext_vector_type(4))) float f4;    // MFMA accumulator

static constexpr int T_STEPS = 128;
static constexpr int BTOT    = 2048;
static constexpr int HD      = 256;
static constexpr int NG      = 768;   // 3*H
static constexpr int LOUT    = 100;

__device__ __forceinline__ short f2bf(float f){
  unsigned u = __builtin_bit_cast(unsigned, f);
  unsigned r = (u + 0x7FFFu + ((u >> 16) & 1u)) >> 16;   // RNE
  return (short)(unsigned short)r;
}
__device__ __forceinline__ float bf2f(short s){
  unsigned u = ((unsigned)(unsigned short)s) << 16;
  return __builtin_bit_cast(float, u);
}
__device__ __forceinline__ f4 mfma16(bh8 a, bh8 b, f4 c){
  return __builtin_amdgcn_mfma_f32_16x16x32_bf16(a, b, c, 0, 0, 0);
}
__device__ __forceinline__ float sigm(float x){
  return __builtin_amdgcn_rcpf(1.f + __expf(-x));
}
__device__ __forceinline__ float tanh_f(float x){
  return 1.f - 2.f*__builtin_amdgcn_rcpf(1.f + __expf(2.f*x));
}

// ---- prep: E0g = per-thread-permuted bf16(emb @ w_ih0^T + biases) (verified r7-14) ----
__global__ void e0g_kernel(const float* __restrict__ emb, const float* __restrict__ w_ih0,
                           const float* __restrict__ b_ih0, const float* __restrict__ b_hh0,
                           short* __restrict__ E0g)
{
  int tid = blockIdx.x*blockDim.x + threadIdx.x;
  if (tid >= 64*NG) return;
  int v = tid / NG, n = tid % NG;
  const float4* er = (const float4*)(emb + (size_t)v*HD);
  const float4* wr = (const float4*)(w_ih0 + (size_t)n*HD);
  float s = 0.f;
#pragma unroll 4
  for (int k=0;k<HD/4;++k){
    float4 a = er[k], b = wr[k];
    s += a.x*b.x + a.y*b.y + a.z*b.z + a.w*b.w;
  }
  s += b_ih0[n];
  if (n < 512) s += b_hh0[n];
  int g = n >> 8, j = n & 255;
  int wid = j >> 5, c = (j >> 4) & 1, l15 = j & 15;
  E0g[(size_t)v*1024 + wid*128 + l15*8 + g*2 + c] = f2bf(s);
}

// ---- prep: pack weights into fragment-linear bf16 tiles (verified r1-14) ----
__global__ void pack_kernel(const float* __restrict__ w_hh0, const float* __restrict__ w_ih1,
                            const float* __restrict__ w_hh1, const float* __restrict__ w1,
                            const float* __restrict__ w2, short* __restrict__ pack)
{
  int tid = blockIdx.x*blockDim.x + threadIdx.x;
  if (tid >= 1336*64) return;
  int t = tid >> 6, lane = tid & 63;
  int l15 = lane & 15, lq = lane >> 4;
  const float* src = nullptr;
  bool zero = false;
  if (t < 1152){
    int m = t/384, tt = t%384, ct = tt/8, kt = tt%8;
    int n = ct*16 + l15;
    const float* Wm = (m==0) ? w_hh0 : (m==1 ? w_ih1 : w_hh1);
    src = Wm + (size_t)n*HD + kt*32 + lq*8;
  } else if (t < 1280){
    int tt = t - 1152, w = tt/16, rem = tt%16, ntt = rem/8, kt = rem%8;
    int n = w*32 + ntt*16 + l15;
    src = w1 + (size_t)n*HD + kt*32 + lq*8;
  } else {
    int tt = t - 1280, ntt = tt/8, kt = tt%8;
    int n = ntt*16 + l15;
    if (n < LOUT) src = w2 + (size_t)n*HD + kt*32 + lq*8;
    else zero = true;
  }
  bh8 o;
#pragma unroll
  for (int e=0;e<8;++e) o[e] = zero ? (short)0 : f2bf(src[e]);
  ((bh8*)pack)[tid] = o;
}

// ====== scan bodies (byte-identical r9/r12/r14 logic) ======

__device__ __forceinline__ void layer0_body(
    int bid, const int* __restrict__ tokens, const short* __restrict__ E0g,
    const short* __restrict__ pack, const float* __restrict__ b_hh0,
    short* __restrict__ s0c, short* __restrict__ h0g, int tc, int Tc,
    short (&st)[2][16*264])
{
  const int tid = threadIdx.x;
  const int wid = tid >> 6;
  const int lane = tid & 63;
  const int l15 = lane & 15, lq = lane >> 4;
  const int b0 = bid * 16;

  bh8 W[3][2][8];
  {
    const bh8* pt = (const bh8*)pack;
#pragma unroll
    for (int g=0;g<3;++g)
#pragma unroll
      for (int c=0;c<2;++c)
#pragma unroll
        for (int kt=0;kt<8;++kt)
          W[g][c][kt] = pt[(size_t)((g*16 + wid*2 + c)*8 + kt)*64 + lane];
  }
  float bhn0[2];
#pragma unroll
  for (int c=0;c<2;++c) bhn0[c] = b_hh0[512 + wid*32 + c*16 + l15];

  float h0s[2][4];
  if (tc == 0){
#pragma unroll
    for (int c=0;c<2;++c)
#pragma unroll
      for (int r=0;r<4;++r) h0s[c][r] = 0.f;
    for (int i=tid;i<16*264;i+=512) st[0][i] = 0;
  } else {
#pragma unroll
    for (int c=0;c<2;++c)
#pragma unroll
      for (int r=0;r<4;++r)
        h0s[c][r] = bf2f(h0g[(size_t)(b0 + lq*4 + r)*HD + wid*32 + c*16 + l15]);
    for (int i=tid;i<16*256;i+=512)
      st[0][(i>>8)*264 + (i&255)] = h0g[(size_t)(b0 + (i>>8))*HD + (i&255)];
  }

  const int e0base = wid*128 + l15*8;
  bh8 ev[4];
  {
    const int tg0 = tc*Tc;
    int tokr[4];
#pragma unroll
    for (int r=0;r<4;++r) tokr[r] = tokens[(size_t)tg0*BTOT + b0 + lq*4 + r];
#pragma unroll
    for (int r=0;r<4;++r)
      ev[r] = *(const bh8*)(E0g + (size_t)tokr[r]*1024 + e0base);
  }
  __syncthreads();

  const f4 zf = {0.f,0.f,0.f,0.f};
  const int crow = tid >> 5, ccol8 = (tid & 31)*8;

#pragma unroll 1
  for (int t=0; t<Tc; ++t){
    const int p = t & 1;
    const int tg = tc*Tc + t;
    const int tn = (tg+1 < T_STEPS) ? tg+1 : T_STEPS-1;
    int tokn[4];
#pragma unroll
    for (int r=0;r<4;++r) tokn[r] = tokens[(size_t)tn*BTOT + b0 + lq*4 + r];
    f4 acc[3][2];
#pragma unroll
    for (int g=0;g<3;++g){ acc[g][0]=zf; acc[g][1]=zf; }
    {
      const short* sp = &st[p][l15*264 + lq*8];
#pragma unroll
      for (int kt=0;kt<8;++kt){
        bh8 a = *(const bh8*)(sp + kt*32);
#pragma unroll
        for (int g=0;g<3;++g){
          acc[g][0] = mfma16(a, W[g][0][kt], acc[g][0]);
          acc[g][1] = mfma16(a, W[g][1][kt], acc[g][1]);
        }
      }
    }
    if (t > 0){
      bh8 cv = *(const bh8*)(&st[p][crow*264 + ccol8]);
      *(bh8*)(s0c + ((size_t)(t-1)*BTOT + b0 + crow)*HD + ccol8) = cv;
    }
    {
      short* stw = st[p^1];
#pragma unroll
      for (int c=0;c<2;++c){
        const int jh = wid*32 + c*16 + l15;
#pragma unroll
        for (int r4=0;r4<4;++r4){
          const int row = lq*4 + r4;
          const float er = bf2f(ev[r4][c]);
          const float ez = bf2f(ev[r4][2+c]);
          const float en = bf2f(ev[r4][4+c]);
          const float rg = sigm(acc[0][c][r4] + er);
          const float zg = sigm(acc[1][c][r4] + ez);
          const float ng = tanh_f(en + rg*(acc[2][c][r4] + bhn0[c]));
          const float h = ng + zg*(h0s[c][r4] - ng);
          h0s[c][r4] = h;
          stw[row*264 + jh] = f2bf(h);
        }
      }
    }
#pragma unroll
    for (int r=0;r<4;++r)
      ev[r] = *(const bh8*)(E0g + (size_t)tokn[r]*1024 + e0base);
    __syncthreads();
  }
  {
    bh8 cv = *(const bh8*)(&st[Tc & 1][crow*264 + ccol8]);
    *(bh8*)(s0c + ((size_t)(Tc-1)*BTOT + b0 + crow)*HD + ccol8) = cv;
    *(bh8*)(h0g + ((size_t)(b0 + crow))*HD + ccol8) = cv;
  }
}

__device__ __forceinline__ void layer1_body(
    int bid, const int* __restrict__ lens, const short* __restrict__ gi1p,
    const short* __restrict__ pack, const float* __restrict__ b_hh1,
    short* __restrict__ h1g, short* __restrict__ outbuf, int tc, int Tc,
    short (&st)[2][16*264])
{
  const int tid = threadIdx.x;
  const int wid = tid >> 6;
  const int lane = tid & 63;
  const int l15 = lane & 15, lq = lane >> 4;
  const int b0 = bid * 16;
  const int bblk = bid;

  bh8 W[3][2][8];
  {
    const bh8* pt = (const bh8*)pack;
#pragma unroll
    for (int g=0;g<3;++g)
#pragma unroll
      for (int c=0;c<2;++c)
#pragma unroll
        for (int kt=0;kt<8;++kt)
          W[g][c][kt] = pt[(size_t)(768 + (g*16 + wid*2 + c)*8 + kt)*64 + lane];
  }
  float bhn1[2];
#pragma unroll
  for (int c=0;c<2;++c) bhn1[c] = b_hh1[512 + wid*32 + c*16 + l15];

  int mylens[4];
#pragma unroll
  for (int r=0;r<4;++r) mylens[r] = lens[b0 + lq*4 + r];

  float h1s[2][4];
  if (tc == 0){
#pragma unroll
    for (int c=0;c<2;++c)
#pragma unroll
      for (int r=0;r<4;++r) h1s[c][r] = 0.f;
    for (int i=tid;i<16*264;i+=512) st[0][i] = 0;
  } else {
#pragma unroll
    for (int c=0;c<2;++c)
#pragma unroll
      for (int r=0;r<4;++r)
        h1s[c][r] = bf2f(h1g[(size_t)(b0 + lq*4 + r)*HD + wid*32 + c*16 + l15]);
    for (int i=tid;i<16*256;i+=512)
      st[0][(i>>8)*264 + (i&255)] = h1g[(size_t)(b0 + (i>>8))*HD + (i&255)];
  }

  bh8 gv[3];
#pragma unroll
  for (int g=0;g<3;++g)
    gv[g] = *(const bh8*)(gi1p + ((size_t)bblk*512 + tid)*24 + g*8);
  __syncthreads();

  const f4 zf = {0.f,0.f,0.f,0.f};
  const int crow = tid >> 5, ccol8 = (tid & 31)*8;

#pragma unroll 1
  for (int t=0; t<Tc; ++t){
    const int p = t & 1;
    const int tg = tc*Tc + t;
    f4 acc[3][2];
#pragma unroll
    for (int g=0;g<3;++g){ acc[g][0]=zf; acc[g][1]=zf; }
    {
      const short* sp = &st[p][l15*264 + lq*8];
#pragma unroll
      for (int kt=0;kt<8;++kt){
        bh8 a = *(const bh8*)(sp + kt*32);
#pragma unroll
        for (int g=0;g<3;++g){
          acc[g][0] = mfma16(a, W[g][0][kt], acc[g][0]);
          acc[g][1] = mfma16(a, W[g][1][kt], acc[g][1]);
        }
      }
    }
    {
      short* stw = st[p^1];
#pragma unroll
      for (int c=0;c<2;++c){
        const int jh = wid*32 + c*16 + l15;
#pragma unroll
        for (int r4=0;r4<4;++r4){
          const int row = lq*4 + r4;
          const float gr = bf2f(gv[0][c*4+r4]);
          const float gz = bf2f(gv[1][c*4+r4]);
          const float gn = bf2f(gv[2][c*4+r4]);
          const float rg = sigm(acc[0][c][r4] + gr);
          const float zg = sigm(acc[1][c][r4] + gz);
          const float ng = tanh_f(gn + rg*(acc[2][c][r4] + bhn1[c]));
          const float h = ng + zg*(h1s[c][r4] - ng);
          h1s[c][r4] = h;
          const short hb = f2bf(h);
          stw[row*264 + jh] = hb;
          if (tg == mylens[r4]) outbuf[(size_t)(b0 + row)*HD + jh] = hb;
        }
      }
    }
    if (t+1 < Tc){
#pragma unroll
      for (int g=0;g<3;++g)
        gv[g] = *(const bh8*)(gi1p + (((size_t)(t+1)*128 + bblk)*512 + tid)*24 + g*8);
    }
    __syncthreads();
  }
  {
    bh8 cv = *(const bh8*)(&st[Tc & 1][crow*264 + ccol8]);
    *(bh8*)(h1g + ((size_t)(b0 + crow))*HD + ccol8) = cv;
  }
}

// ---- gi1 role (verified r9 gi1_gemm logic; grid-slice of 128 wgs, stride 128) ----
__device__ __forceinline__ void gi1_body(
    int bid, const short* __restrict__ s0c, const short* __restrict__ pack,
    const float* __restrict__ b_ih1, const float* __restrict__ b_hh1,
    short* __restrict__ gi1p, int NC, short (&ab)[2][16*264])
{
  const int tid = threadIdx.x;
  const int wid = tid >> 6;
  const int lane = tid & 63;
  const int l15 = lane & 15, lq = lane >> 4;

  bh8 W[6][8];
#pragma unroll
  for (int i=0;i<6;++i)
#pragma unroll
    for (int kt=0;kt<8;++kt)
      W[i][kt] = ((const bh8*)pack)[(size_t)(384 + (wid*6+i)*8 + kt)*64 + lane];

  float bi[6];
  int offo[6];
#pragma unroll
  for (int i=0;i<6;++i){
    const int gc = (wid*6+i)*16 + l15;
    bi[i] = b_ih1[gc] + ((gc < 512) ? b_hh1[gc] : 0.f);
    const int g = gc >> 8, j = gc & 255;
    const int widp = j >> 5, c = (j >> 4) & 1;
    const int tidp = widp*64 + lq*16 + l15;
    offo[i] = tidp*24 + g*8 + c*4;
  }

  int ci = bid;
  if (ci >= NC) return;
  bh8 sr = *(const bh8*)(s0c + (size_t)ci*4096 + tid*8);
  *(bh8*)(&ab[0][(tid>>5)*264 + (tid&31)*8]) = sr;
  __syncthreads();

  const f4 zf = {0.f,0.f,0.f,0.f};
  int p = 0;
#pragma unroll 1
  for (; ci < NC; ci += 128){
    const int cin = ci + 128;
    const bool more = (cin < NC);
    if (more) sr = *(const bh8*)(s0c + (size_t)cin*4096 + tid*8);
    f4 acc[6];
#pragma unroll
    for (int i=0;i<6;++i) acc[i] = zf;
    const short* sp = &ab[p][l15*264 + lq*8];
#pragma unroll
    for (int kt=0;kt<8;++kt){
      bh8 a = *(const bh8*)(sp + kt*32);
#pragma unroll
      for (int i=0;i<6;++i) acc[i] = mfma16(a, W[i][kt], acc[i]);
    }
#pragma unroll
    for (int i=0;i<6;++i){
      sh4 v;
#pragma unroll
      for (int r4=0;r4<4;++r4) v[r4] = f2bf(acc[i][r4] + bi[i]);
      *(sh4*)(gi1p + (size_t)ci*512*24 + offo[i]) = v;
    }
    if (more)
      *(bh8*)(&ab[p^1][(tid>>5)*264 + (tid&31)*8]) = sr;
    p ^= 1;
    __syncthreads();
  }
}

// ---- 3-role fat kernel: F(k) = L0(tc0) || gi1(tcg) || L1(tc1), depth-3 pipeline ----
// All cross-role dependencies cross a kernel boundary; s0c/gi1p double-buffered by parity.
__global__ __launch_bounds__(512, 1)
void scan_fat3(const int* __restrict__ tokens, const short* __restrict__ E0g,
               const short* __restrict__ pack, const float* __restrict__ b_hh0,
               short* __restrict__ s0cA, short* __restrict__ s0cB, short* __restrict__ h0g,
               const int* __restrict__ lens,
               short* __restrict__ gi1pA, short* __restrict__ gi1pB,
               const float* __restrict__ b_ih1, const float* __restrict__ b_hh1,
               short* __restrict__ h1g, short* __restrict__ outbuf,
               int tc0, int tcg, int tc1, int Tc)
{
  __shared__ __align__(16) short st[2][16*264];
  const int bx = blockIdx.x;
  if (bx < 128){
    if (tc0 >= 0){
      short* s0c_w = (tc0 & 1) ? s0cB : s0cA;
      layer0_body(bx, tokens, E0g, pack, b_hh0, s0c_w, h0g, tc0, Tc, st);
    }
  } else if (bx < 256){
    if (tc1 >= 0){
      const short* gi1p_r = (tc1 & 1) ? gi1pB : gi1pA;
      layer1_body(bx - 128, lens, gi1p_r, pack, b_hh1, h1g, outbuf, tc1, Tc, st);
    }
  } else {
    if (tcg >= 0){
      const short* s0c_r = (tcg & 1) ? s0cB : s0cA;
      short* gi1p_w = (tcg & 1) ? gi1pB : gi1pA;
      gi1_body(bx - 256, s0c_r, pack, b_ih1, b_hh1, gi1p_w, Tc*128, st);
    }
  }
}

// ---- phase D: head (verified r1-14) ----
__global__ __launch_bounds__(512, 1)
void head_kernel(const short* __restrict__ outbuf, const short* __restrict__ pack,
                 const float* __restrict__ b1, const float* __restrict__ b2,
                 float* __restrict__ out)
{
  const int tid = threadIdx.x;
  const int wid = tid >> 6;
  const int lane = tid & 63;
  const int l15 = lane & 15, lq = lane >> 4;
  const int b0 = blockIdx.x * 32;

  __shared__ __align__(16) short zA[32*264];
  __shared__ __align__(16) short zB[32*264];
  __shared__ float b1s[HD], b2s[112];
  if (tid < HD)  b1s[tid] = b1[tid];
  if (tid < 112) b2s[tid] = (tid < LOUT) ? b2[tid] : 0.f;

  for (int i=tid;i<32*256;i+=512){
    int row = i >> 8, col = i & 255;
    zA[row*264 + col] = outbuf[(size_t)(b0 + row)*HD + col];
  }
  __syncthreads();

  const f4 zf = {0.f,0.f,0.f,0.f};
  const int afrag = l15*264 + lq*8;
  constexpr int RT1 = 16*264;
  const bh8* packW1 = (const bh8*)pack + (size_t)(1152 + wid*16)*64 + lane;
  const bh8* packW2 = (const bh8*)pack + (size_t)(1280 + wid*8 )*64 + lane;

  {
    f4 az[2][2]; az[0][0]=zf; az[0][1]=zf; az[1][0]=zf; az[1][1]=zf;
#pragma unroll
    for (int kt=0;kt<8;++kt){
      bh8 a0 = *(const bh8*)(&zA[afrag + kt*32]);
      bh8 a1 = *(const bh8*)(&zA[afrag + RT1 + kt*32]);
#pragma unroll
      for (int nt=0;nt<2;++nt){
        bh8 b = packW1[(nt*8+kt)*64];
        az[nt][0] = mfma16(a0, b, az[nt][0]);
        az[nt][1] = mfma16(a1, b, az[nt][1]);
      }
    }
#pragma unroll
    for (int rt=0;rt<2;++rt)
#pragma unroll
      for (int nt=0;nt<2;++nt){
        const int jb = wid*32 + nt*16 + l15;
#pragma unroll
        for (int r4=0;r4<4;++r4){
          float v = az[nt][rt][r4] + b1s[jb];
          v = (v >= 0.f) ? v : 0.01f*v;     // LeakyReLU
          zB[(rt*16+lq*4+r4)*264 + jb] = f2bf(v);
        }
      }
  }
  __syncthreads();

  if (wid < 7){
    f4 acc2[2]; acc2[0]=zf; acc2[1]=zf;
#pragma unroll
    for (int kt=0;kt<8;++kt){
      bh8 a0 = *(const bh8*)(&zB[afrag + kt*32]);
      bh8 a1 = *(const bh8*)(&zB[afrag + RT1 + kt*32]);
      bh8 b = packW2[kt*64];
      acc2[0] = mfma16(a0, b, acc2[0]);
      acc2[1] = mfma16(a1, b, acc2[1]);
    }
    const int n2 = wid*16 + l15;
    if (n2 < LOUT){
#pragma unroll
      for (int rt=0;rt<2;++rt)
#pragma unroll
        for (int r4=0;r4<4;++r4)
          out[(size_t)(b0 + rt*16 + lq*4 + r4)*LOUT + n2] = acc2[rt][r4] + b2s[n2];
    }
  }
}

extern "C" void kernel_launch(void* const* d_in, const int* in_sizes, int n_in,
                              void* d_out, int out_size, void* d_ws, size_t ws_size,
                              hipStream_t stream)
{
  const int*   tokens = (const int*)  d_in[0];
  const int*   lens   = (const int*)  d_in[1];
  const float* emb    = (const float*)d_in[2];
  const float* w_ih0  = (const float*)d_in[3];
  const float* w_hh0  = (const float*)d_in[4];
  const float* b_ih0  = (const float*)d_in[5];
  const float* b_hh0  = (const float*)d_in[6];
  const float* w_ih1  = (const float*)d_in[7];
  const float* w_hh1  = (const float*)d_in[8];
  const float* b_ih1  = (const float*)d_in[9];
  const float* b_hh1  = (const float*)d_in[10];
  const float* w1     = (const float*)d_in[11];
  const float* b1     = (const float*)d_in[12];
  const float* w2     = (const float*)d_in[13];
  const float* b2     = (const float*)d_in[14];

  char* ws = (char*)d_ws;
  size_t off = 0;
  short* pack = (short*)(ws + off); off += (size_t)1336*1024;       // 1.34 MB
  short* E0g  = (short*)(ws + off); off += (size_t)64*1024*2;       // 128 KB
  short* h0g  = (short*)(ws + off); off += (size_t)BTOT*HD*2;       // 1 MB
  short* h1g  = (short*)(ws + off); off += (size_t)BTOT*HD*2;       // 1 MB
  short* outb = (short*)(ws + off); off += (size_t)BTOT*HD*2;       // 1 MB
  const size_t fixed = off;
  const size_t perT = (size_t)BTOT*HD*2 + (size_t)BTOT*NG*2;        // 4 MB / step / buffer
  int Tc = 16;                                                      // depth-3 pipeline: 2x buffers
  while (Tc > 1 && fixed + (size_t)2*Tc*perT > ws_size) Tc >>= 1;   // 2x(s0c+gi1p); Tc=16 = 138.8 MB
  const size_t s0cE  = (size_t)Tc*BTOT*HD;                          // elems per s0c buffer
  const size_t gi1pE = (size_t)Tc*BTOT*NG;
  short* s0cA  = (short*)(ws + fixed);
  short* s0cB  = s0cA  + s0cE;
  short* gi1pA = s0cB  + s0cE;
  short* gi1pB = gi1pA + gi1pE;

  e0g_kernel <<<(64*NG + 255)/256,   256, 0, stream>>>(emb, w_ih0, b_ih0, b_hh0, E0g);
  pack_kernel<<<(1336*64 + 255)/256, 256, 0, stream>>>(w_hh0, w_ih1, w_hh1, w1, w2, pack);

  const int nch = T_STEPS / Tc;
  // depth-3 software pipeline: F(k) = L0(k) || gi1(k-1) || L1(k-2)
  for (int k = 0; k <= nch + 1; ++k){
    const int tc0 = (k < nch) ? k : -1;
    const int tcg = (k-1 >= 0 && k-1 < nch) ? k-1 : -1;
    const int tc1 = (k-2 >= 0) ? k-2 : -1;
    scan_fat3<<<384, 512, 0, stream>>>(tokens, E0g, pack, b_hh0,
                                       s0cA, s0cB, h0g, lens,
                                       gi1pA, gi1pB, b_ih1, b_hh1,
                                       h1g, outb, tc0, tcg, tc1, Tc);
  }
  head_kernel<<<BTOT/32, 512, 0, stream>>>(outb, pack, b1, b2, (float*)d_out);
}

// Round 16
// 606.050 us; speedup vs baseline: 1.0691x; 1.0691x over previous
//
#include <hip/hip_runtime.h>
#include <hip/hip_bf16.h>

typedef __attribute__((ext_vector_type(8))) short bh8;   // 8 x bf16 (4 VGPRs)
typedef __attribute__((ext_vector_type(4))) short sh4;   // 4 x bf16
typedef __attribute__((ext_vector_type(4))) float f4;    // MFMA accumulator

static constexpr int T_STEPS = 128;
static constexpr int BTOT    = 2048;
static constexpr int HD      = 256;
static constexpr int NG      = 768;   // 3*H
static constexpr int LOUT    = 100;

__device__ __forceinline__ short f2bf(float f){
  unsigned u = __builtin_bit_cast(unsigned, f);
  unsigned r = (u + 0x7FFFu + ((u >> 16) & 1u)) >> 16;   // RNE
  return (short)(unsigned short)r;
}
__device__ __forceinline__ float bf2f(short s){
  unsigned u = ((unsigned)(unsigned short)s) << 16;
  return __builtin_bit_cast(float, u);
}
__device__ __forceinline__ f4 mfma16(bh8 a, bh8 b, f4 c){
  return __builtin_amdgcn_mfma_f32_16x16x32_bf16(a, b, c, 0, 0, 0);
}
__device__ __forceinline__ float sigm(float x){
  return __builtin_amdgcn_rcpf(1.f + __expf(-x));
}
__device__ __forceinline__ float tanh_f(float x){
  return 1.f - 2.f*__builtin_amdgcn_rcpf(1.f + __expf(2.f*x));
}

// ---- prep: E0g = per-thread-permuted bf16(emb @ w_ih0^T + biases) (verified r7-15) ----
__global__ void e0g_kernel(const float* __restrict__ emb, const float* __restrict__ w_ih0,
                           const float* __restrict__ b_ih0, const float* __restrict__ b_hh0,
                           short* __restrict__ E0g)
{
  int tid = blockIdx.x*blockDim.x + threadIdx.x;
  if (tid >= 64*NG) return;
  int v = tid / NG, n = tid % NG;
  const float4* er = (const float4*)(emb + (size_t)v*HD);
  const float4* wr = (const float4*)(w_ih0 + (size_t)n*HD);
  float s = 0.f;
#pragma unroll 4
  for (int k=0;k<HD/4;++k){
    float4 a = er[k], b = wr[k];
    s += a.x*b.x + a.y*b.y + a.z*b.z + a.w*b.w;
  }
  s += b_ih0[n];
  if (n < 512) s += b_hh0[n];
  int g = n >> 8, j = n & 255;
  int wid = j >> 5, c = (j >> 4) & 1, l15 = j & 15;
  E0g[(size_t)v*1024 + wid*128 + l15*8 + g*2 + c] = f2bf(s);
}

// ---- prep: pack weights into fragment-linear bf16 tiles (verified r1-15) ----
__global__ void pack_kernel(const float* __restrict__ w_hh0, const float* __restrict__ w_ih1,
                            const float* __restrict__ w_hh1, const float* __restrict__ w1,
                            const float* __restrict__ w2, short* __restrict__ pack)
{
  int tid = blockIdx.x*blockDim.x + threadIdx.x;
  if (tid >= 1336*64) return;
  int t = tid >> 6, lane = tid & 63;
  int l15 = lane & 15, lq = lane >> 4;
  const float* src = nullptr;
  bool zero = false;
  if (t < 1152){
    int m = t/384, tt = t%384, ct = tt/8, kt = tt%8;
    int n = ct*16 + l15;
    const float* Wm = (m==0) ? w_hh0 : (m==1 ? w_ih1 : w_hh1);
    src = Wm + (size_t)n*HD + kt*32 + lq*8;
  } else if (t < 1280){
    int tt = t - 1152, w = tt/16, rem = tt%16, ntt = rem/8, kt = rem%8;
    int n = w*32 + ntt*16 + l15;
    src = w1 + (size_t)n*HD + kt*32 + lq*8;
  } else {
    int tt = t - 1280, ntt = tt/8, kt = tt%8;
    int n = ntt*16 + l15;
    if (n < LOUT) src = w2 + (size_t)n*HD + kt*32 + lq*8;
    else zero = true;
  }
  bh8 o;
#pragma unroll
  for (int e=0;e<8;++e) o[e] = zero ? (short)0 : f2bf(src[e]);
  ((bh8*)pack)[tid] = o;
}

// ====== scan bodies (exact r9/r12/r14: kt-outer 6-chain MFMA, natural load placement) ======

__device__ __forceinline__ void layer0_body(
    int bid, const int* __restrict__ tokens, const short* __restrict__ E0g,
    const short* __restrict__ pack, const float* __restrict__ b_hh0,
    short* __restrict__ s0c, short* __restrict__ h0g, int tc, int Tc,
    short (&st)[2][16*264])
{
  const int tid = threadIdx.x;
  const int wid = tid >> 6;
  const int lane = tid & 63;
  const int l15 = lane & 15, lq = lane >> 4;
  const int b0 = bid * 16;

  bh8 W[3][2][8];
  {
    const bh8* pt = (const bh8*)pack;
#pragma unroll
    for (int g=0;g<3;++g)
#pragma unroll
      for (int c=0;c<2;++c)
#pragma unroll
        for (int kt=0;kt<8;++kt)
          W[g][c][kt] = pt[(size_t)((g*16 + wid*2 + c)*8 + kt)*64 + lane];
  }
  float bhn0[2];
#pragma unroll
  for (int c=0;c<2;++c) bhn0[c] = b_hh0[512 + wid*32 + c*16 + l15];

  float h0s[2][4];
  if (tc == 0){
#pragma unroll
    for (int c=0;c<2;++c)
#pragma unroll
      for (int r=0;r<4;++r) h0s[c][r] = 0.f;
    for (int i=tid;i<16*264;i+=512) st[0][i] = 0;
  } else {
#pragma unroll
    for (int c=0;c<2;++c)
#pragma unroll
      for (int r=0;r<4;++r)
        h0s[c][r] = bf2f(h0g[(size_t)(b0 + lq*4 + r)*HD + wid*32 + c*16 + l15]);
    for (int i=tid;i<16*256;i+=512)
      st[0][(i>>8)*264 + (i&255)] = h0g[(size_t)(b0 + (i>>8))*HD + (i&255)];
  }

  const int e0base = wid*128 + l15*8;
  bh8 ev[4];
  {
    const int tg0 = tc*Tc;
    int tokr[4];
#pragma unroll
    for (int r=0;r<4;++r) tokr[r] = tokens[(size_t)tg0*BTOT + b0 + lq*4 + r];
#pragma unroll
    for (int r=0;r<4;++r)
      ev[r] = *(const bh8*)(E0g + (size_t)tokr[r]*1024 + e0base);
  }
  __syncthreads();

  const f4 zf = {0.f,0.f,0.f,0.f};
  const int crow = tid >> 5, ccol8 = (tid & 31)*8;

#pragma unroll 1
  for (int t=0; t<Tc; ++t){
    const int p = t & 1;
    const int tg = tc*Tc + t;
    const int tn = (tg+1 < T_STEPS) ? tg+1 : T_STEPS-1;
    int tokn[4];
#pragma unroll
    for (int r=0;r<4;++r) tokn[r] = tokens[(size_t)tn*BTOT + b0 + lq*4 + r];
    f4 acc[3][2];
#pragma unroll
    for (int g=0;g<3;++g){ acc[g][0]=zf; acc[g][1]=zf; }
    {
      const short* sp = &st[p][l15*264 + lq*8];
#pragma unroll
      for (int kt=0;kt<8;++kt){
        bh8 a = *(const bh8*)(sp + kt*32);
#pragma unroll
        for (int g=0;g<3;++g){
          acc[g][0] = mfma16(a, W[g][0][kt], acc[g][0]);
          acc[g][1] = mfma16(a, W[g][1][kt], acc[g][1]);
        }
      }
    }
    if (t > 0){
      bh8 cv = *(const bh8*)(&st[p][crow*264 + ccol8]);
      *(bh8*)(s0c + ((size_t)(t-1)*BTOT + b0 + crow)*HD + ccol8) = cv;
    }
    {
      short* stw = st[p^1];
#pragma unroll
      for (int c=0;c<2;++c){
        const int jh = wid*32 + c*16 + l15;
#pragma unroll
        for (int r4=0;r4<4;++r4){
          const int row = lq*4 + r4;
          const float er = bf2f(ev[r4][c]);
          const float ez = bf2f(ev[r4][2+c]);
          const float en = bf2f(ev[r4][4+c]);
          const float rg = sigm(acc[0][c][r4] + er);
          const float zg = sigm(acc[1][c][r4] + ez);
          const float ng = tanh_f(en + rg*(acc[2][c][r4] + bhn0[c]));
          const float h = ng + zg*(h0s[c][r4] - ng);
          h0s[c][r4] = h;
          stw[row*264 + jh] = f2bf(h);
        }
      }
    }
#pragma unroll
    for (int r=0;r<4;++r)
      ev[r] = *(const bh8*)(E0g + (size_t)tokn[r]*1024 + e0base);
    __syncthreads();
  }
  {
    bh8 cv = *(const bh8*)(&st[Tc & 1][crow*264 + ccol8]);
    *(bh8*)(s0c + ((size_t)(Tc-1)*BTOT + b0 + crow)*HD + ccol8) = cv;
    *(bh8*)(h0g + ((size_t)(b0 + crow))*HD + ccol8) = cv;
  }
}

__device__ __forceinline__ void layer1_body(
    int bid, const int* __restrict__ lens, const short* __restrict__ gi1p,
    const short* __restrict__ pack, const float* __restrict__ b_hh1,
    short* __restrict__ h1g, short* __restrict__ outbuf, int tc, int Tc,
    short (&st)[2][16*264])
{
  const int tid = threadIdx.x;
  const int wid = tid >> 6;
  const int lane = tid & 63;
  const int l15 = lane & 15, lq = lane >> 4;
  const int b0 = bid * 16;
  const int bblk = bid;

  bh8 W[3][2][8];
  {
    const bh8* pt = (const bh8*)pack;
#pragma unroll
    for (int g=0;g<3;++g)
#pragma unroll
      for (int c=0;c<2;++c)
#pragma unroll
        for (int kt=0;kt<8;++kt)
          W[g][c][kt] = pt[(size_t)(768 + (g*16 + wid*2 + c)*8 + kt)*64 + lane];
  }
  float bhn1[2];
#pragma unroll
  for (int c=0;c<2;++c) bhn1[c] = b_hh1[512 + wid*32 + c*16 + l15];

  int mylens[4];
#pragma unroll
  for (int r=0;r<4;++r) mylens[r] = lens[b0 + lq*4 + r];

  float h1s[2][4];
  if (tc == 0){
#pragma unroll
    for (int c=0;c<2;++c)
#pragma unroll
      for (int r=0;r<4;++r) h1s[c][r] = 0.f;
    for (int i=tid;i<16*264;i+=512) st[0][i] = 0;
  } else {
#pragma unroll
    for (int c=0;c<2;++c)
#pragma unroll
      for (int r=0;r<4;++r)
        h1s[c][r] = bf2f(h1g[(size_t)(b0 + lq*4 + r)*HD + wid*32 + c*16 + l15]);
    for (int i=tid;i<16*256;i+=512)
      st[0][(i>>8)*264 + (i&255)] = h1g[(size_t)(b0 + (i>>8))*HD + (i&255)];
  }

  bh8 gv[3];
#pragma unroll
  for (int g=0;g<3;++g)
    gv[g] = *(const bh8*)(gi1p + ((size_t)bblk*512 + tid)*24 + g*8);
  __syncthreads();

  const f4 zf = {0.f,0.f,0.f,0.f};
  const int crow = tid >> 5, ccol8 = (tid & 31)*8;

#pragma unroll 1
  for (int t=0; t<Tc; ++t){
    const int p = t & 1;
    const int tg = tc*Tc + t;
    f4 acc[3][2];
#pragma unroll
    for (int g=0;g<3;++g){ acc[g][0]=zf; acc[g][1]=zf; }
    {
      const short* sp = &st[p][l15*264 + lq*8];
#pragma unroll
      for (int kt=0;kt<8;++kt){
        bh8 a = *(const bh8*)(sp + kt*32);
#pragma unroll
        for (int g=0;g<3;++g){
          acc[g][0] = mfma16(a, W[g][0][kt], acc[g][0]);
          acc[g][1] = mfma16(a, W[g][1][kt], acc[g][1]);
        }
      }
    }
    {
      short* stw = st[p^1];
#pragma unroll
      for (int c=0;c<2;++c){
        const int jh = wid*32 + c*16 + l15;
#pragma unroll
        for (int r4=0;r4<4;++r4){
          const int row = lq*4 + r4;
          const float gr = bf2f(gv[0][c*4+r4]);
          const float gz = bf2f(gv[1][c*4+r4]);
          const float gn = bf2f(gv[2][c*4+r4]);
          const float rg = sigm(acc[0][c][r4] + gr);
          const float zg = sigm(acc[1][c][r4] + gz);
          const float ng = tanh_f(gn + rg*(acc[2][c][r4] + bhn1[c]));
          const float h = ng + zg*(h1s[c][r4] - ng);
          h1s[c][r4] = h;
          const short hb = f2bf(h);
          stw[row*264 + jh] = hb;
          if (tg == mylens[r4]) outbuf[(size_t)(b0 + row)*HD + jh] = hb;
        }
      }
    }
    if (t+1 < Tc){
#pragma unroll
      for (int g=0;g<3;++g)
        gv[g] = *(const bh8*)(gi1p + (((size_t)(t+1)*128 + bblk)*512 + tid)*24 + g*8);
    }
    __syncthreads();
  }
  {
    bh8 cv = *(const bh8*)(&st[Tc & 1][crow*264 + ccol8]);
    *(bh8*)(h1g + ((size_t)(b0 + crow))*HD + ccol8) = cv;
  }
}

// ---- fat kernel: blocks 0-127 run layer0(tc0), blocks 128-255 run layer1(tc1) ----
__global__ __launch_bounds__(512, 1)
void scan_fat(const int* __restrict__ tokens, const short* __restrict__ E0g,
              const short* __restrict__ pack, const float* __restrict__ b_hh0,
              short* __restrict__ s0c, short* __restrict__ h0g,
              const int* __restrict__ lens, const short* __restrict__ gi1p,
              const float* __restrict__ b_hh1, short* __restrict__ h1g,
              short* __restrict__ outbuf, int tc0, int tc1, int Tc)
{
  __shared__ __align__(16) short st[2][16*264];
  const int bx = blockIdx.x;
  if (bx < 128){
    if (tc0 >= 0)
      layer0_body(bx, tokens, E0g, pack, b_hh0, s0c, h0g, tc0, Tc, st);
  } else {
    if (tc1 >= 0)
      layer1_body(bx - 128, lens, gi1p, pack, b_hh1, h1g, outbuf, tc1, Tc, st);
  }
}

// ---- phase B: gi1 GEMM (verified r9-14: 512 thr, 2 waves/SIMD) ----
__global__ __launch_bounds__(512, 1)
void gi1_gemm(const short* __restrict__ s0c, const short* __restrict__ pack,
              const float* __restrict__ b_ih1, const float* __restrict__ b_hh1,
              short* __restrict__ gi1p, int NC)
{
  const int tid = threadIdx.x;
  const int wid = tid >> 6;
  const int lane = tid & 63;
  const int l15 = lane & 15, lq = lane >> 4;

  __shared__ __align__(16) short ab[2][16*264];

  bh8 W[6][8];
#pragma unroll
  for (int i=0;i<6;++i)
#pragma unroll
    for (int kt=0;kt<8;++kt)
      W[i][kt] = ((const bh8*)pack)[(size_t)(384 + (wid*6+i)*8 + kt)*64 + lane];

  float bi[6];
  int offo[6];
#pragma unroll
  for (int i=0;i<6;++i){
    const int gc = (wid*6+i)*16 + l15;
    bi[i] = b_ih1[gc] + ((gc < 512) ? b_hh1[gc] : 0.f);
    const int g = gc >> 8, j = gc & 255;
    const int widp = j >> 5, c = (j >> 4) & 1;
    const int tidp = widp*64 + lq*16 + l15;
    offo[i] = tidp*24 + g*8 + c*4;
  }

  int ci = blockIdx.x;
  if (ci >= NC) return;
  bh8 sr = *(const bh8*)(s0c + (size_t)ci*4096 + tid*8);
  *(bh8*)(&ab[0][(tid>>5)*264 + (tid&31)*8]) = sr;
  __syncthreads();

  const f4 zf = {0.f,0.f,0.f,0.f};
  int p = 0;
#pragma unroll 1
  for (; ci < NC; ci += gridDim.x){
    const int cin = ci + (int)gridDim.x;
    const bool more = (cin < NC);
    if (more) sr = *(const bh8*)(s0c + (size_t)cin*4096 + tid*8);
    f4 acc[6];
#pragma unroll
    for (int i=0;i<6;++i) acc[i] = zf;
    const short* sp = &ab[p][l15*264 + lq*8];
#pragma unroll
    for (int kt=0;kt<8;++kt){
      bh8 a = *(const bh8*)(sp + kt*32);
#pragma unroll
      for (int i=0;i<6;++i) acc[i] = mfma16(a, W[i][kt], acc[i]);
    }
#pragma unroll
    for (int i=0;i<6;++i){
      sh4 v;
#pragma unroll
      for (int r4=0;r4<4;++r4) v[r4] = f2bf(acc[i][r4] + bi[i]);
      *(sh4*)(gi1p + (size_t)ci*512*24 + offo[i]) = v;
    }
    if (more)
      *(bh8*)(&ab[p^1][(tid>>5)*264 + (tid&31)*8]) = sr;
    p ^= 1;
    __syncthreads();
  }
}

// ---- phase D: head (verified r1-15) ----
__global__ __launch_bounds__(512, 1)
void head_kernel(const short* __restrict__ outbuf, const short* __restrict__ pack,
                 const float* __restrict__ b1, const float* __restrict__ b2,
                 float* __restrict__ out)
{
  const int tid = threadIdx.x;
  const int wid = tid >> 6;
  const int lane = tid & 63;
  const int l15 = lane & 15, lq = lane >> 4;
  const int b0 = blockIdx.x * 32;

  __shared__ __align__(16) short zA[32*264];
  __shared__ __align__(16) short zB[32*264];
  __shared__ float b1s[HD], b2s[112];
  if (tid < HD)  b1s[tid] = b1[tid];
  if (tid < 112) b2s[tid] = (tid < LOUT) ? b2[tid] : 0.f;

  for (int i=tid;i<32*256;i+=512){
    int row = i >> 8, col = i & 255;
    zA[row*264 + col] = outbuf[(size_t)(b0 + row)*HD + col];
  }
  __syncthreads();

  const f4 zf = {0.f,0.f,0.f,0.f};
  const int afrag = l15*264 + lq*8;
  constexpr int RT1 = 16*264;
  const bh8* packW1 = (const bh8*)pack + (size_t)(1152 + wid*16)*64 + lane;
  const bh8* packW2 = (const bh8*)pack + (size_t)(1280 + wid*8 )*64 + lane;

  {
    f4 az[2][2]; az[0][0]=zf; az[0][1]=zf; az[1][0]=zf; az[1][1]=zf;
#pragma unroll
    for (int kt=0;kt<8;++kt){
      bh8 a0 = *(const bh8*)(&zA[afrag + kt*32]);
      bh8 a1 = *(const bh8*)(&zA[afrag + RT1 + kt*32]);
#pragma unroll
      for (int nt=0;nt<2;++nt){
        bh8 b = packW1[(nt*8+kt)*64];
        az[nt][0] = mfma16(a0, b, az[nt][0]);
        az[nt][1] = mfma16(a1, b, az[nt][1]);
      }
    }
#pragma unroll
    for (int rt=0;rt<2;++rt)
#pragma unroll
      for (int nt=0;nt<2;++nt){
        const int jb = wid*32 + nt*16 + l15;
#pragma unroll
        for (int r4=0;r4<4;++r4){
          float v = az[nt][rt][r4] + b1s[jb];
          v = (v >= 0.f) ? v : 0.01f*v;     // LeakyReLU
          zB[(rt*16+lq*4+r4)*264 + jb] = f2bf(v);
        }
      }
  }
  __syncthreads();

  if (wid < 7){
    f4 acc2[2]; acc2[0]=zf; acc2[1]=zf;
#pragma unroll
    for (int kt=0;kt<8;++kt){
      bh8 a0 = *(const bh8*)(&zB[afrag + kt*32]);
      bh8 a1 = *(const bh8*)(&zB[afrag + RT1 + kt*32]);
      bh8 b = packW2[kt*64];
      acc2[0] = mfma16(a0, b, acc2[0]);
      acc2[1] = mfma16(a1, b, acc2[1]);
    }
    const int n2 = wid*16 + l15;
    if (n2 < LOUT){
#pragma unroll
      for (int rt=0;rt<2;++rt)
#pragma unroll
        for (int r4=0;r4<4;++r4)
          out[(size_t)(b0 + rt*16 + lq*4 + r4)*LOUT + n2] = acc2[rt][r4] + b2s[n2];
    }
  }
}

extern "C" void kernel_launch(void* const* d_in, const int* in_sizes, int n_in,
                              void* d_out, int out_size, void* d_ws, size_t ws_size,
                              hipStream_t stream)
{
  const int*   tokens = (const int*)  d_in[0];
  const int*   lens   = (const int*)  d_in[1];
  const float* emb    = (const float*)d_in[2];
  const float* w_ih0  = (const float*)d_in[3];
  const float* w_hh0  = (const float*)d_in[4];
  const float* b_ih0  = (const float*)d_in[5];
  const float* b_hh0  = (const float*)d_in[6];
  const float* w_ih1  = (const float*)d_in[7];
  const float* w_hh1  = (const float*)d_in[8];
  const float* b_ih1  = (const float*)d_in[9];
  const float* b_hh1  = (const float*)d_in[10];
  const float* w1     = (const float*)d_in[11];
  const float* b1     = (const float*)d_in[12];
  const float* w2     = (const float*)d_in[13];
  const float* b2     = (const float*)d_in[14];

  char* ws = (char*)d_ws;
  size_t off = 0;
  short* pack = (short*)(ws + off); off += (size_t)1336*1024;       // 1.34 MB
  short* E0g  = (short*)(ws + off); off += (size_t)64*1024*2;       // 128 KB
  short* h0g  = (short*)(ws + off); off += (size_t)BTOT*HD*2;       // 1 MB
  short* h1g  = (short*)(ws + off); off += (size_t)BTOT*HD*2;       // 1 MB
  short* outb = (short*)(ws + off); off += (size_t)BTOT*HD*2;       // 1 MB
  const size_t fixed = off;
  const size_t perT = (size_t)BTOT*HD*2 + (size_t)BTOT*NG*2;        // 4 MB / step
  int Tc = T_STEPS;
  while (Tc > 1 && fixed + (size_t)Tc*perT > ws_size) Tc >>= 1;
  if (Tc > 32) Tc = 32;                                             // pipeline depth cap
  short* s0c  = (short*)(ws + fixed);
  short* gi1p = (short*)(ws + fixed + (size_t)Tc*BTOT*HD*2);

  e0g_kernel <<<(64*NG + 255)/256,   256, 0, stream>>>(emb, w_ih0, b_ih0, b_hh0, E0g);
  pack_kernel<<<(1336*64 + 255)/256, 256, 0, stream>>>(w_hh0, w_ih1, w_hh1, w1, w2, pack);

  const int nch = T_STEPS / Tc;
  // software pipeline across chunks: F(k) = L0(k) || L1(k-1);  G(k) between.
  for (int k = 0; k <= nch; ++k){
    const int tc0 = (k < nch) ? k : -1;
    const int tc1 = k - 1;
    scan_fat<<<256, 512, 0, stream>>>(tokens, E0g, pack, b_hh0, s0c, h0g,
                                      lens, gi1p, b_hh1, h1g, outb, tc0, tc1, Tc);
    if (k < nch)
      gi1_gemm<<<256, 512, 0, stream>>>(s0c, pack, b_ih1, b_hh1, gi1p, Tc*BTOT/16);
  }
  head_kernel<<<BTOT/32, 512, 0, stream>>>(outb, pack, b1, b2, (float*)d_out);
}